// Round 5
// baseline (3176.661 us; speedup 1.0000x reference)
//
#include <hip/hip_runtime.h>
#include <math.h>
#include <stdint.h>

// Problem constants
#define DIMX 512
#define KD 32
#define NH 16
#define VD 128
#define NTOK 1024
#define NBATCH 16
#define QKVO 3072   // NH*(VD+2*KD)
#define OUTD 2048   // NH*VD
#define SCALE_QK 0.17677669529663687f
#define LN_EPS 1e-5f

// ---------------------------------------------------------------------------
// Guard kernel: marks output when workspace is too small (diagnostic, no fault)
// ---------------------------------------------------------------------------
__global__ void ws_too_small_kernel(float* out, int n)
{
    int i = blockIdx.x * blockDim.x + threadIdx.x;
    if (i < n) out[i] = -12345.0f;
}

// ---------------------------------------------------------------------------
// Kernel 1: LayerNorm, one block (128 thr) per row of 512 floats
// ---------------------------------------------------------------------------
__global__ __launch_bounds__(128)
void ln_kernel(const float* __restrict__ x, const float* __restrict__ g,
               const float* __restrict__ be, float* __restrict__ xn)
{
    const size_t row = blockIdx.x;
    const int t = threadIdx.x;
    const float4 v = ((const float4*)(x + row * DIMX))[t];
    float s  = v.x + v.y + v.z + v.w;
    float ss = v.x*v.x + v.y*v.y + v.z*v.z + v.w*v.w;
#pragma unroll
    for (int o = 32; o; o >>= 1) { s += __shfl_down(s, o); ss += __shfl_down(ss, o); }
    __shared__ float sb[4];
    if ((t & 63) == 0) { sb[t >> 6] = s; sb[2 + (t >> 6)] = ss; }
    __syncthreads();
    s = sb[0] + sb[1]; ss = sb[2] + sb[3];
    const float mu = s * (1.f / DIMX);
    const float rs = rsqrtf(ss * (1.f / DIMX) - mu * mu + LN_EPS);
    const float4 gv = ((const float4*)g)[t];
    const float4 bv = ((const float4*)be)[t];
    float4 o;
    o.x = (v.x - mu) * rs * gv.x + bv.x;
    o.y = (v.y - mu) * rs * gv.y + bv.y;
    o.z = (v.z - mu) * rs * gv.z + bv.z;
    o.w = (v.w - mu) * rs * gv.w + bv.w;
    ((float4*)(xn + row * DIMX))[t] = o;
}

// ---------------------------------------------------------------------------
// Kernel 2/4: C[M,N] = A[M,K] * B[N,K]^T + bias  (both row-major over K)
// 128x128 tile, BK=8, 256 threads, 8x8 per thread.
// EPI=0: plain row-major store to C (+bias per col)
// EPI=1: scatter into q[g*NH,N,32], k[g*NH,N,32], v[g*NH,N,128] (batch-local)
// ---------------------------------------------------------------------------
template <int EPI>
__global__ __launch_bounds__(256, 2)
void gemm_abt(const float* __restrict__ A, const float* __restrict__ B,
              const float* __restrict__ bias, float* __restrict__ C,
              int M, int N, int K,
              float* __restrict__ qo, float* __restrict__ ko, float* __restrict__ vo)
{
    __shared__ float As[8][132];
    __shared__ float Bs[8][132];
    const int t  = threadIdx.x;
    const int bm = blockIdx.x, bn = blockIdx.y;
    const int tx = t & 15, ty = t >> 4;
    const int lr = t >> 1;          // 0..127 (tile row for staging)
    const int lk = (t & 1) * 4;     // 0 or 4 (k offset for staging)
    const float* Ap = A + (size_t)(bm * 128 + lr) * K + lk;
    const float* Bp = B + (size_t)(bn * 128 + lr) * K + lk;
    float acc[2][2][4][4] = {};
    for (int k0 = 0; k0 < K; k0 += 8) {
        const float4 av = *(const float4*)(Ap + k0);
        const float4 bv = *(const float4*)(Bp + k0);
        __syncthreads();
        As[lk + 0][lr] = av.x; As[lk + 1][lr] = av.y; As[lk + 2][lr] = av.z; As[lk + 3][lr] = av.w;
        Bs[lk + 0][lr] = bv.x; Bs[lk + 1][lr] = bv.y; Bs[lk + 2][lr] = bv.z; Bs[lk + 3][lr] = bv.w;
        __syncthreads();
#pragma unroll
        for (int kk = 0; kk < 8; kk++) {
            const float4 a0 = *(const float4*)&As[kk][ty * 4];
            const float4 a1 = *(const float4*)&As[kk][ty * 4 + 64];
            const float4 b0 = *(const float4*)&Bs[kk][tx * 4];
            const float4 b1 = *(const float4*)&Bs[kk][tx * 4 + 64];
            const float ar[8] = {a0.x, a0.y, a0.z, a0.w, a1.x, a1.y, a1.z, a1.w};
            const float br[8] = {b0.x, b0.y, b0.z, b0.w, b1.x, b1.y, b1.z, b1.w};
#pragma unroll
            for (int i = 0; i < 8; i++)
#pragma unroll
                for (int j = 0; j < 8; j++)
                    acc[i >> 2][j >> 2][i & 3][j & 3] += ar[i] * br[j];
        }
    }

    if (EPI == 0) {
#pragma unroll
        for (int mi = 0; mi < 2; mi++)
#pragma unroll
            for (int r = 0; r < 4; r++) {
                const int row = bm * 128 + mi * 64 + ty * 4 + r;
#pragma unroll
                for (int nj = 0; nj < 2; nj++) {
                    const int col = bn * 128 + nj * 64 + tx * 4;
                    const float4 bb = *(const float4*)(bias + col);
                    float4 o;
                    o.x = acc[mi][nj][r][0] + bb.x;
                    o.y = acc[mi][nj][r][1] + bb.y;
                    o.z = acc[mi][nj][r][2] + bb.z;
                    o.w = acc[mi][nj][r][3] + bb.w;
                    *(float4*)(C + (size_t)row * N + col) = o;
                }
            }
    } else {
#pragma unroll
        for (int mi = 0; mi < 2; mi++)
#pragma unroll
            for (int r = 0; r < 4; r++) {
                const int row = bm * 128 + mi * 64 + ty * 4 + r;
                const int bb = row >> 10, nn = row & 1023;   // batch-local index
#pragma unroll
                for (int nj = 0; nj < 2; nj++)
#pragma unroll
                    for (int c = 0; c < 4; c++) {
                        const int col = bn * 128 + nj * 64 + tx * 4 + c;
                        const float val = acc[mi][nj][r][c] + bias[col];
                        const int h  = col / 192;
                        const int rr = col - h * 192;
                        const size_t base = ((size_t)(bb * NH + h) * NTOK + nn);
                        if (rr < KD)           qo[base * KD + rr] = val;
                        else if (rr < 2 * KD)  ko[base * KD + rr - KD] = val;
                        else                   vo[base * VD + rr - 2 * KD] = val;
                    }
            }
    }
}

// ---------------------------------------------------------------------------
// Kernel 3: flash-style attention per (local b, h). 64-query tile, 32-key chunks.
// q,k: [g*NH, 1024, 32]; v: [g*NH, 1024, 128]; out: [g, N, H, 128] (group-local)
// ---------------------------------------------------------------------------
__global__ __launch_bounds__(256, 2)
void attn_kernel(const float* __restrict__ q, const float* __restrict__ kg,
                 const float* __restrict__ vg, const float* __restrict__ ab,
                 const int* __restrict__ bidx, float* __restrict__ out)
{
    __shared__ float Qs[32][68];   // [kdim][qrow]
    __shared__ float Ks[32][36];   // [kdim][mrow]
    __shared__ float Vs[32][132];  // [mrow][vdim]
    __shared__ float Ss[64][36];   // [qrow][mrow]
    __shared__ float Mrow[64], Lrow[64], Alpha[64];

    const int t  = threadIdx.x;
    const int bh = blockIdx.y;
    const int b  = bh >> 4, h = bh & 15;   // b is group-local
    const int n0 = blockIdx.x * 64;
    const float* qp  = q  + (size_t)bh * NTOK * KD;
    const float* kp  = kg + (size_t)bh * NTOK * KD;
    const float* vp  = vg + (size_t)bh * NTOK * VD;
    const float* abh = ab + h * NTOK;

    // stage Q tile transposed: Qs[c][r] = q[n0+r][c]
#pragma unroll
    for (int i = 0; i < 2; i++) {
        const int idx = t + i * 256;
        const int r = idx >> 3, c4 = (idx & 7) * 4;
        const float4 vv = *(const float4*)(qp + (size_t)(n0 + r) * KD + c4);
        Qs[c4 + 0][r] = vv.x; Qs[c4 + 1][r] = vv.y; Qs[c4 + 2][r] = vv.z; Qs[c4 + 3][r] = vv.w;
    }
    if (t < 64) { Mrow[t] = -INFINITY; Lrow[t] = 0.f; }

    const int tx = t & 15, ty = t >> 4;
    float oacc[4][8] = {};

    for (int m0 = 0; m0 < NTOK; m0 += 32) {
        __syncthreads();
        {   // stage K chunk transposed
            const int r = t >> 3, c4 = (t & 7) * 4;
            const float4 kv = *(const float4*)(kp + (size_t)(m0 + r) * KD + c4);
            Ks[c4 + 0][r] = kv.x; Ks[c4 + 1][r] = kv.y; Ks[c4 + 2][r] = kv.z; Ks[c4 + 3][r] = kv.w;
        }
#pragma unroll
        for (int i = 0; i < 4; i++) {  // stage V chunk
            const int idx = t + i * 256;
            const int r = idx >> 5, c4 = (idx & 31) * 4;
            *(float4*)&Vs[r][c4] = *(const float4*)(vp + (size_t)(m0 + r) * VD + c4);
        }
        __syncthreads();

        // S = Q K^T : each thread 4 rows x 2 cols
        float sacc[4][2] = {};
#pragma unroll
        for (int c = 0; c < 32; c++) {
            const float4 qv = *(const float4*)&Qs[c][ty * 4];
            const float2 kv = *(const float2*)&Ks[c][tx * 2];
            sacc[0][0] += qv.x * kv.x; sacc[0][1] += qv.x * kv.y;
            sacc[1][0] += qv.y * kv.x; sacc[1][1] += qv.y * kv.y;
            sacc[2][0] += qv.z * kv.x; sacc[2][1] += qv.z * kv.y;
            sacc[3][0] += qv.w * kv.x; sacc[3][1] += qv.w * kv.y;
        }
#pragma unroll
        for (int r = 0; r < 4; r++) {
            const int n = n0 + ty * 4 + r;
            const int2 iv = *(const int2*)&bidx[(size_t)n * NTOK + m0 + tx * 2];
            float2 o;
            o.x = sacc[r][0] * SCALE_QK + abh[iv.x];
            o.y = sacc[r][1] * SCALE_QK + abh[iv.y];
            *(float2*)&Ss[ty * 4 + r][tx * 2] = o;
        }
        __syncthreads();

        // online softmax: wave wv owns rows wv*16..wv*16+15; 2 rows per pass
        {
            const int wv = t >> 6, ln = t & 63;
#pragma unroll
            for (int rr = 0; rr < 8; rr++) {
                const int row = wv * 16 + rr * 2 + (ln >> 5);
                const int col = ln & 31;
                const float s = Ss[row][col];
                float mx = s;
#pragma unroll
                for (int msk = 16; msk; msk >>= 1) mx = fmaxf(mx, __shfl_xor(mx, msk));
                const float mo = Mrow[row];
                const float mn = fmaxf(mo, mx);
                const float p = __expf(s - mn);
                Ss[row][col] = p;
                float sum = p;
#pragma unroll
                for (int msk = 16; msk; msk >>= 1) sum += __shfl_xor(sum, msk);
                if (col == 0) {
                    const float a = __expf(mo - mn);
                    Mrow[row] = mn; Alpha[row] = a;
                    Lrow[row] = Lrow[row] * a + sum;
                }
            }
        }
        __syncthreads();

        // PV accumulate with rescale
        float al[4];
#pragma unroll
        for (int r = 0; r < 4; r++) al[r] = Alpha[ty * 4 + r];
#pragma unroll
        for (int r = 0; r < 4; r++)
#pragma unroll
            for (int c = 0; c < 8; c++) oacc[r][c] *= al[r];
#pragma unroll
        for (int k4 = 0; k4 < 8; k4++) {
            float4 p4[4];
#pragma unroll
            for (int r = 0; r < 4; r++) p4[r] = *(const float4*)&Ss[ty * 4 + r][k4 * 4];
#pragma unroll
            for (int u = 0; u < 4; u++) {
                const int kk = k4 * 4 + u;
                const float4 v0 = *(const float4*)&Vs[kk][tx * 4];
                const float4 v1 = *(const float4*)&Vs[kk][tx * 4 + 64];
#pragma unroll
                for (int r = 0; r < 4; r++) {
                    const float pv = (&p4[r].x)[u];
                    oacc[r][0] += pv * v0.x; oacc[r][1] += pv * v0.y;
                    oacc[r][2] += pv * v0.z; oacc[r][3] += pv * v0.w;
                    oacc[r][4] += pv * v1.x; oacc[r][5] += pv * v1.y;
                    oacc[r][6] += pv * v1.z; oacc[r][7] += pv * v1.w;
                }
            }
        }
    }
    __syncthreads();
#pragma unroll
    for (int r = 0; r < 4; r++) {
        const int row = ty * 4 + r;
        const float inv = 1.f / Lrow[row];
        float* op = out + ((size_t)(b * NTOK + n0 + row) * NH + h) * VD;
        float4 o0, o1;
        o0.x = oacc[r][0] * inv; o0.y = oacc[r][1] * inv;
        o0.z = oacc[r][2] * inv; o0.w = oacc[r][3] * inv;
        o1.x = oacc[r][4] * inv; o1.y = oacc[r][5] * inv;
        o1.z = oacc[r][6] * inv; o1.w = oacc[r][7] * inv;
        *(float4*)(op + tx * 4)      = o0;
        *(float4*)(op + 64 + tx * 4) = o1;
    }
}

// ---------------------------------------------------------------------------
// Launch. Adaptive batch-grouping to fit unknown ws_size.
// Per-batch scratch (floats): q,k: 2*NH*NTOK*KD = 1,048,576 | v: NH*NTOK*VD =
// 2,097,152 | ao: NTOK*OUTD = 2,097,152  => 5,242,880 floats = 20 MiB/batch.
// g = largest {16,8,4,2,1} with 20g MiB <= ws_size. xn lives in d_out: LN
// writes all rows once; group b0's proj overwrites exactly the rows its own
// qkv GEMM already consumed (stream-ordered, later groups' rows untouched).
// ---------------------------------------------------------------------------
extern "C" void kernel_launch(void* const* d_in, const int* in_sizes, int n_in,
                              void* d_out, int out_size, void* d_ws, size_t ws_size,
                              hipStream_t stream)
{
    const float* x     = (const float*)d_in[0];
    const float* gamma = (const float*)d_in[1];
    const float* beta  = (const float*)d_in[2];
    const float* Wqkv  = (const float*)d_in[3];
    const float* bqkv  = (const float*)d_in[4];
    const float* Wproj = (const float*)d_in[5];
    const float* bproj = (const float*)d_in[6];
    const float* ab    = (const float*)d_in[7];
    const int*   bidx  = (const int*)d_in[8];
    float* out = (float*)d_out;

    const size_t per_b = 2ull * NH * NTOK * KD    // q, k
                       + (size_t)NH * NTOK * VD   // v
                       + (size_t)NTOK * OUTD;     // ao
    int g = 0;
    for (int cand = 16; cand >= 1; cand >>= 1)
        if ((size_t)cand * per_b * sizeof(float) <= ws_size) { g = cand; break; }
    if (g == 0) {
        ws_too_small_kernel<<<(out_size + 255) / 256, 256, 0, stream>>>(out, out_size);
        return;
    }

    float* ws = (float*)d_ws;
    float* q  = ws;
    float* k  = q + (size_t)g * NH * NTOK * KD;
    float* v  = k + (size_t)g * NH * NTOK * KD;
    float* ao = v + (size_t)g * NH * NTOK * VD;
    float* xn = out;  // d_out doubles as xn scratch

    ln_kernel<<<16384, 128, 0, stream>>>(x, gamma, beta, xn);
    for (int b0 = 0; b0 < NBATCH; b0 += g) {
        float* xrows = xn + (size_t)b0 * NTOK * DIMX;
        gemm_abt<1><<<dim3(g * 8, 24), 256, 0, stream>>>(
            xrows, Wqkv, bqkv, nullptr, g * NTOK, QKVO, DIMX, q, k, v);
        attn_kernel<<<dim3(16, g * 16), 256, 0, stream>>>(q, k, v, ab, bidx, ao);
        gemm_abt<0><<<dim3(g * 8, 4), 256, 0, stream>>>(
            ao, Wproj, bproj, xrows, g * NTOK, DIMX, OUTD, nullptr, nullptr, nullptr);
    }
}

// Round 6
// 2048.534 us; speedup vs baseline: 1.5507x; 1.5507x over previous
//
#include <hip/hip_runtime.h>
#include <math.h>
#include <stdint.h>

// Problem constants
#define DIMX 512
#define KD 32
#define NH 16
#define VD 128
#define NTOK 1024
#define NBATCH 16
#define QKVO 3072   // NH*(VD+2*KD)
#define OUTD 2048   // NH*VD
#define SCALE_QK 0.17677669529663687f
#define LN_EPS 1e-5f

typedef __attribute__((ext_vector_type(8))) short bf16x8;   // 8 bf16 in 4 VGPRs
typedef __attribute__((ext_vector_type(4))) short short4v;  // 4 bf16 (8B)
typedef __attribute__((ext_vector_type(4))) float f32x4;

__device__ __forceinline__ short f2bf(float f) {   // fp32 -> bf16 RNE
    uint32_t u = __builtin_bit_cast(uint32_t, f);
    u += 0x7FFFu + ((u >> 16) & 1u);
    return (short)(u >> 16);
}

// ---------------------------------------------------------------------------
// Guard kernel: marks output when workspace is too small (diagnostic, no fault)
// ---------------------------------------------------------------------------
__global__ void ws_too_small_kernel(float* out, int n)
{
    int i = blockIdx.x * blockDim.x + threadIdx.x;
    if (i < n) out[i] = -12345.0f;
}

// ---------------------------------------------------------------------------
// Kernel 1: LayerNorm, one block (128 thr) per row of 512 floats
// ---------------------------------------------------------------------------
__global__ __launch_bounds__(128)
void ln_kernel(const float* __restrict__ x, const float* __restrict__ g,
               const float* __restrict__ be, float* __restrict__ xn)
{
    const size_t row = blockIdx.x;
    const int t = threadIdx.x;
    const float4 v = ((const float4*)(x + row * DIMX))[t];
    float s  = v.x + v.y + v.z + v.w;
    float ss = v.x*v.x + v.y*v.y + v.z*v.z + v.w*v.w;
#pragma unroll
    for (int o = 32; o; o >>= 1) { s += __shfl_down(s, o); ss += __shfl_down(ss, o); }
    __shared__ float sb[4];
    if ((t & 63) == 0) { sb[t >> 6] = s; sb[2 + (t >> 6)] = ss; }
    __syncthreads();
    s = sb[0] + sb[1]; ss = sb[2] + sb[3];
    const float mu = s * (1.f / DIMX);
    const float rs = rsqrtf(ss * (1.f / DIMX) - mu * mu + LN_EPS);
    const float4 gv = ((const float4*)g)[t];
    const float4 bv = ((const float4*)be)[t];
    float4 o;
    o.x = (v.x - mu) * rs * gv.x + bv.x;
    o.y = (v.y - mu) * rs * gv.y + bv.y;
    o.z = (v.z - mu) * rs * gv.z + bv.z;
    o.w = (v.w - mu) * rs * gv.w + bv.w;
    ((float4*)(xn + row * DIMX))[t] = o;
}

// ---------------------------------------------------------------------------
// Kernel 2/4: C[M,N] = A[M,K] * B[N,K]^T + bias  (both row-major over K)
// 128x128 tile, BK=8, 256 threads, 8x8 per thread.
// EPI=0: plain fp32 row-major store to C (+bias per col)
// EPI=1: scatter BF16 into q[bh,n,32], k[bh,n,32], v[bh,n,128] (batch-local)
// ---------------------------------------------------------------------------
template <int EPI>
__global__ __launch_bounds__(256, 2)
void gemm_abt(const float* __restrict__ A, const float* __restrict__ B,
              const float* __restrict__ bias, float* __restrict__ C,
              int M, int N, int K,
              short* __restrict__ qo, short* __restrict__ ko, short* __restrict__ vo)
{
    __shared__ float As[8][132];
    __shared__ float Bs[8][132];
    const int t  = threadIdx.x;
    const int bm = blockIdx.x, bn = blockIdx.y;
    const int tx = t & 15, ty = t >> 4;
    const int lr = t >> 1;          // 0..127 (tile row for staging)
    const int lk = (t & 1) * 4;     // 0 or 4 (k offset for staging)
    const float* Ap = A + (size_t)(bm * 128 + lr) * K + lk;
    const float* Bp = B + (size_t)(bn * 128 + lr) * K + lk;
    float acc[2][2][4][4] = {};
    for (int k0 = 0; k0 < K; k0 += 8) {
        const float4 av = *(const float4*)(Ap + k0);
        const float4 bv = *(const float4*)(Bp + k0);
        __syncthreads();
        As[lk + 0][lr] = av.x; As[lk + 1][lr] = av.y; As[lk + 2][lr] = av.z; As[lk + 3][lr] = av.w;
        Bs[lk + 0][lr] = bv.x; Bs[lk + 1][lr] = bv.y; Bs[lk + 2][lr] = bv.z; Bs[lk + 3][lr] = bv.w;
        __syncthreads();
#pragma unroll
        for (int kk = 0; kk < 8; kk++) {
            const float4 a0 = *(const float4*)&As[kk][ty * 4];
            const float4 a1 = *(const float4*)&As[kk][ty * 4 + 64];
            const float4 b0 = *(const float4*)&Bs[kk][tx * 4];
            const float4 b1 = *(const float4*)&Bs[kk][tx * 4 + 64];
            const float ar[8] = {a0.x, a0.y, a0.z, a0.w, a1.x, a1.y, a1.z, a1.w};
            const float br[8] = {b0.x, b0.y, b0.z, b0.w, b1.x, b1.y, b1.z, b1.w};
#pragma unroll
            for (int i = 0; i < 8; i++)
#pragma unroll
                for (int j = 0; j < 8; j++)
                    acc[i >> 2][j >> 2][i & 3][j & 3] += ar[i] * br[j];
        }
    }

    if (EPI == 0) {
#pragma unroll
        for (int mi = 0; mi < 2; mi++)
#pragma unroll
            for (int r = 0; r < 4; r++) {
                const int row = bm * 128 + mi * 64 + ty * 4 + r;
#pragma unroll
                for (int nj = 0; nj < 2; nj++) {
                    const int col = bn * 128 + nj * 64 + tx * 4;
                    const float4 bb = *(const float4*)(bias + col);
                    float4 o;
                    o.x = acc[mi][nj][r][0] + bb.x;
                    o.y = acc[mi][nj][r][1] + bb.y;
                    o.z = acc[mi][nj][r][2] + bb.z;
                    o.w = acc[mi][nj][r][3] + bb.w;
                    *(float4*)(C + (size_t)row * N + col) = o;
                }
            }
    } else {
#pragma unroll
        for (int mi = 0; mi < 2; mi++)
#pragma unroll
            for (int r = 0; r < 4; r++) {
                const int row = bm * 128 + mi * 64 + ty * 4 + r;
                const int bb = row >> 10, nn = row & 1023;   // batch-local
#pragma unroll
                for (int nj = 0; nj < 2; nj++) {
                    const int col0 = bn * 128 + nj * 64 + tx * 4;   // 4-col group never straddles a 32-boundary
                    const int h  = col0 / 192;
                    const int rr = col0 - h * 192;
                    short4v s4;
#pragma unroll
                    for (int c = 0; c < 4; c++) s4[c] = f2bf(acc[mi][nj][r][c] + bias[col0 + c]);
                    const size_t base = ((size_t)(bb * NH + h) * NTOK + nn);
                    if (rr < KD)           *(short4v*)(qo + base * KD + rr) = s4;
                    else if (rr < 2 * KD)  *(short4v*)(ko + base * KD + rr - KD) = s4;
                    else                   *(short4v*)(vo + base * VD + rr - 2 * KD) = s4;
                }
            }
    }
}

// ---------------------------------------------------------------------------
// Kernel 3a: transpose v[bh][n][d] (bf16) -> vt[bh][d][n] (bf16), 64x64 tiles
// ---------------------------------------------------------------------------
__global__ __launch_bounds__(256)
void vtrans_kernel(const short* __restrict__ v, short* __restrict__ vt)
{
    __shared__ short T[64][72];
    const int bh  = blockIdx.y;
    const int n0  = (blockIdx.x & 15) * 64;
    const int d0  = (blockIdx.x >> 4) * 64;
    const int t   = threadIdx.x;
    const short* vp  = v  + (size_t)bh * NTOK * VD;
    short*       vtp = vt + (size_t)bh * VD * NTOK;
    {
        const int i = t >> 2, jo = (t & 3) * 16;
        const bf16x8 a = *(const bf16x8*)(vp + (size_t)(n0 + i) * VD + d0 + jo);
        const bf16x8 b = *(const bf16x8*)(vp + (size_t)(n0 + i) * VD + d0 + jo + 8);
        *(bf16x8*)&T[i][jo]     = a;
        *(bf16x8*)&T[i][jo + 8] = b;
    }
    __syncthreads();
    {
        const int j = t >> 2, io = (t & 3) * 16;
        bf16x8 a, b;
#pragma unroll
        for (int c = 0; c < 8; c++) { a[c] = T[io + c][j]; b[c] = T[io + 8 + c][j]; }
        *(bf16x8*)(vtp + (size_t)(d0 + j) * NTOK + n0 + io)     = a;
        *(bf16x8*)(vtp + (size_t)(d0 + j) * NTOK + n0 + io + 8) = b;
    }
}

// ---------------------------------------------------------------------------
// Kernel 3b: MFMA flash attention. 256 thr = 4 independent waves, each owns
// 16 q-rows; sweeps 64-key tiles. mfma_f32_16x16x32_bf16:
//   A: row=lane&15, k=(lane>>4)*8+j   B: col=lane&15, k=(lane>>4)*8+j
//   D: col=lane&15, row=(lane>>4)*4+reg   [m89-verified layout]
// No __syncthreads; only per-wave LDS for the P round-trip.
// q,k: [bh][1024][32] bf16; vt: [bh][128][1024] bf16; out: [b][n][h][128] fp32
// Block-id swizzle: id%8 = bh%8 -> a head's 16 q-blocks share an XCD's L2.
// ---------------------------------------------------------------------------
__global__ __launch_bounds__(256, 4)
void attn_mfma_kernel(const short* __restrict__ qg, const short* __restrict__ kg,
                      const short* __restrict__ vtg, const float* __restrict__ ab,
                      const int* __restrict__ bidx, float* __restrict__ out)
{
    __shared__ short Ps[4][16][72];   // per-wave P tile [q][m], padded
    const int id = blockIdx.x;
    const int tt = id >> 3;
    const int qb = tt & 15;
    const int bh = (id & 7) + 8 * (tt >> 4);
    const int b = bh >> 4, h = bh & 15;
    const int t = threadIdx.x;
    const int w = t >> 6, lane = t & 63;
    const int lg = lane >> 4, lc = lane & 15;
    const int n0 = qb * 64 + w * 16;          // wave's q-row base
    const short* qp  = qg  + (size_t)bh * NTOK * KD;
    const short* kp  = kg  + (size_t)bh * NTOK * KD;
    const short* vtp = vtg + (size_t)bh * VD * NTOK;
    const float* abh = ab + h * NTOK;

    const bf16x8 aq = *(const bf16x8*)(qp + (size_t)(n0 + lc) * KD + lg * 8);

    f32x4 oacc[8];
#pragma unroll
    for (int i = 0; i < 8; i++) oacc[i] = (f32x4){0.f, 0.f, 0.f, 0.f};
    float mrun[4] = {-INFINITY, -INFINITY, -INFINITY, -INFINITY};
    float lrun[4] = {0.f, 0.f, 0.f, 0.f};

    for (int m0 = 0; m0 < NTOK; m0 += 64) {
        // ---- S = Q K^T (4 sub-tiles of 16 keys, K=32 in one mfma each)
        float sv[4][4];                        // [mt][r]
#pragma unroll
        for (int mt = 0; mt < 4; mt++) {
            const bf16x8 bk = *(const bf16x8*)(kp + (size_t)(m0 + mt * 16 + lc) * KD + lg * 8);
            f32x4 d = (f32x4){0.f, 0.f, 0.f, 0.f};
            d = __builtin_amdgcn_mfma_f32_16x16x32_bf16(aq, bk, d, 0, 0, 0);
#pragma unroll
            for (int r = 0; r < 4; r++) sv[mt][r] = d[r];
        }
        // ---- scale + gathered bias
#pragma unroll
        for (int mt = 0; mt < 4; mt++)
#pragma unroll
            for (int r = 0; r < 4; r++) {
                const int n = n0 + lg * 4 + r;
                const int m = m0 + mt * 16 + lc;
                sv[mt][r] = sv[mt][r] * SCALE_QK + abh[bidx[(size_t)n * NTOK + m]];
            }
        // ---- wave-parallel online softmax (rows live in 16-lane groups)
        float alpha[4];
#pragma unroll
        for (int r = 0; r < 4; r++) {
            float m1 = fmaxf(fmaxf(sv[0][r], sv[1][r]), fmaxf(sv[2][r], sv[3][r]));
#pragma unroll
            for (int msk = 1; msk < 16; msk <<= 1) m1 = fmaxf(m1, __shfl_xor(m1, msk));
            const float mn = fmaxf(mrun[r], m1);
            alpha[r] = __expf(mrun[r] - mn);
            mrun[r] = mn;
        }
#pragma unroll
        for (int mt = 0; mt < 4; mt++)
#pragma unroll
            for (int r = 0; r < 4; r++) sv[mt][r] = __expf(sv[mt][r] - mrun[r]);
#pragma unroll
        for (int r = 0; r < 4; r++) {
            float s1 = (sv[0][r] + sv[1][r]) + (sv[2][r] + sv[3][r]);
#pragma unroll
            for (int msk = 1; msk < 16; msk <<= 1) s1 += __shfl_xor(s1, msk);
            lrun[r] = lrun[r] * alpha[r] + s1;
        }
#pragma unroll
        for (int dt = 0; dt < 8; dt++)
#pragma unroll
            for (int r = 0; r < 4; r++) oacc[dt][r] *= alpha[r];
        // ---- P -> bf16 via per-wave LDS (layout change regs->A-frag)
#pragma unroll
        for (int mt = 0; mt < 4; mt++)
#pragma unroll
            for (int r = 0; r < 4; r++)
                Ps[w][lg * 4 + r][mt * 16 + lc] = f2bf(sv[mt][r]);
        // ---- PV accumulate (compiler inserts lgkmcnt before the ds_read)
#pragma unroll
        for (int mt2 = 0; mt2 < 2; mt2++) {
            const bf16x8 ap = *(const bf16x8*)&Ps[w][lc][mt2 * 32 + lg * 8];
#pragma unroll
            for (int dt = 0; dt < 8; dt++) {
                const bf16x8 bv = *(const bf16x8*)(vtp + (size_t)(dt * 16 + lc) * NTOK + m0 + mt2 * 32 + lg * 8);
                oacc[dt] = __builtin_amdgcn_mfma_f32_16x16x32_bf16(ap, bv, oacc[dt], 0, 0, 0);
            }
        }
    }
    // ---- epilogue
    float inv[4];
#pragma unroll
    for (int r = 0; r < 4; r++) inv[r] = 1.f / lrun[r];
#pragma unroll
    for (int dt = 0; dt < 8; dt++)
#pragma unroll
        for (int r = 0; r < 4; r++)
            out[((size_t)(b * NTOK + n0 + lg * 4 + r) * NH + h) * VD + dt * 16 + lc] =
                oacc[dt][r] * inv[r];
}

// ---------------------------------------------------------------------------
// Launch. Adaptive batch-grouping (ws_size unknown). Per-batch scratch:
// q,k bf16 1MB+1MB | v bf16 4MB | vt bf16 4MB | ao fp32 8MB = 18MB/batch.
// xn lives in d_out (LN writes all rows once; each group's proj overwrites
// exactly the rows its own qkv GEMM already consumed).
// ---------------------------------------------------------------------------
extern "C" void kernel_launch(void* const* d_in, const int* in_sizes, int n_in,
                              void* d_out, int out_size, void* d_ws, size_t ws_size,
                              hipStream_t stream)
{
    const float* x     = (const float*)d_in[0];
    const float* gamma = (const float*)d_in[1];
    const float* beta  = (const float*)d_in[2];
    const float* Wqkv  = (const float*)d_in[3];
    const float* bqkv  = (const float*)d_in[4];
    const float* Wproj = (const float*)d_in[5];
    const float* bproj = (const float*)d_in[6];
    const float* ab    = (const float*)d_in[7];
    const int*   bidx  = (const int*)d_in[8];
    float* out = (float*)d_out;

    const size_t per_b = 2ull * NH * NTOK * KD * 2   // q,k bf16
                       + 2ull * NH * NTOK * VD * 2   // v, vt bf16
                       + (size_t)NTOK * OUTD * 4;    // ao fp32
    int g = 0;
    for (int cand = 16; cand >= 1; cand >>= 1)
        if ((size_t)cand * per_b <= ws_size) { g = cand; break; }
    if (g == 0) {
        ws_too_small_kernel<<<(out_size + 255) / 256, 256, 0, stream>>>(out, out_size);
        return;
    }

    char* p = (char*)d_ws;
    short* qb_ = (short*)p;  p += (size_t)g * NH * NTOK * KD * 2;
    short* kb_ = (short*)p;  p += (size_t)g * NH * NTOK * KD * 2;
    short* vb_ = (short*)p;  p += (size_t)g * NH * NTOK * VD * 2;
    short* vtb = (short*)p;  p += (size_t)g * NH * NTOK * VD * 2;
    float* ao  = (float*)p;
    float* xn  = out;  // d_out doubles as xn scratch

    ln_kernel<<<16384, 128, 0, stream>>>(x, gamma, beta, xn);
    for (int b0 = 0; b0 < NBATCH; b0 += g) {
        float* xrows = xn + (size_t)b0 * NTOK * DIMX;
        gemm_abt<1><<<dim3(g * 8, 24), 256, 0, stream>>>(
            xrows, Wqkv, bqkv, nullptr, g * NTOK, QKVO, DIMX, qb_, kb_, vb_);
        vtrans_kernel<<<dim3(32, g * 16), 256, 0, stream>>>(vb_, vtb);
        attn_mfma_kernel<<<16 * g * 16, 256, 0, stream>>>(qb_, kb_, vtb, ab, bidx, ao);
        gemm_abt<0><<<dim3(g * 8, 4), 256, 0, stream>>>(
            ao, Wproj, bproj, xrows, g * NTOK, DIMX, OUTD, nullptr, nullptr, nullptr);
    }
}

// Round 7
// 998.774 us; speedup vs baseline: 3.1806x; 2.0510x over previous
//
#include <hip/hip_runtime.h>
#include <math.h>
#include <stdint.h>

// Problem constants
#define DIMX 512
#define KD 32
#define NH 16
#define VD 128
#define NTOK 1024
#define NBATCH 16
#define QKVO 3072   // NH*(VD+2*KD)
#define OUTD 2048   // NH*VD
#define SCALE_QK 0.17677669529663687f
#define LN_EPS 1e-5f

typedef __attribute__((ext_vector_type(8))) short bf16x8;   // 8 bf16 in 4 VGPRs
typedef __attribute__((ext_vector_type(4))) short short4v;  // 4 bf16 (8B)
typedef __attribute__((ext_vector_type(4))) float f32x4;

__device__ __forceinline__ short f2bf(float f) {   // fp32 -> bf16 RNE
    uint32_t u = __builtin_bit_cast(uint32_t, f);
    u += 0x7FFFu + ((u >> 16) & 1u);
    return (short)(u >> 16);
}

// ---------------------------------------------------------------------------
// Guard kernel: marks output when workspace is too small (diagnostic, no fault)
// ---------------------------------------------------------------------------
__global__ void ws_too_small_kernel(float* out, int n)
{
    int i = blockIdx.x * blockDim.x + threadIdx.x;
    if (i < n) out[i] = -12345.0f;
}

// ---------------------------------------------------------------------------
// Kernel 0: fp32 -> bf16 weight conversion (vectorized, n multiple of 4)
// ---------------------------------------------------------------------------
__global__ __launch_bounds__(256)
void f2bf_kernel(const float* __restrict__ in, short* __restrict__ out, int n4)
{
    int i = blockIdx.x * blockDim.x + threadIdx.x;
    if (i < n4) {
        const float4 v = ((const float4*)in)[i];
        short4v s;
        s[0] = f2bf(v.x); s[1] = f2bf(v.y); s[2] = f2bf(v.z); s[3] = f2bf(v.w);
        ((short4v*)out)[i] = s;
    }
}

// ---------------------------------------------------------------------------
// Kernel 1: LayerNorm, one block (128 thr) per row of 512 floats -> bf16 out
// ---------------------------------------------------------------------------
__global__ __launch_bounds__(128)
void ln_kernel(const float* __restrict__ x, const float* __restrict__ g,
               const float* __restrict__ be, short* __restrict__ xn)
{
    const size_t row = blockIdx.x;
    const int t = threadIdx.x;
    const float4 v = ((const float4*)(x + row * DIMX))[t];
    float s  = v.x + v.y + v.z + v.w;
    float ss = v.x*v.x + v.y*v.y + v.z*v.z + v.w*v.w;
#pragma unroll
    for (int o = 32; o; o >>= 1) { s += __shfl_down(s, o); ss += __shfl_down(ss, o); }
    __shared__ float sb[4];
    if ((t & 63) == 0) { sb[t >> 6] = s; sb[2 + (t >> 6)] = ss; }
    __syncthreads();
    s = sb[0] + sb[1]; ss = sb[2] + sb[3];
    const float mu = s * (1.f / DIMX);
    const float rs = rsqrtf(ss * (1.f / DIMX) - mu * mu + LN_EPS);
    const float4 gv = ((const float4*)g)[t];
    const float4 bv = ((const float4*)be)[t];
    short4v o;
    o[0] = f2bf((v.x - mu) * rs * gv.x + bv.x);
    o[1] = f2bf((v.y - mu) * rs * gv.y + bv.y);
    o[2] = f2bf((v.z - mu) * rs * gv.z + bv.z);
    o[3] = f2bf((v.w - mu) * rs * gv.w + bv.w);
    *(short4v*)(xn + row * DIMX + t * 4) = o;
}

// ---------------------------------------------------------------------------
// Kernel 2/4: bf16 MFMA GEMM.  C[M,N] = A[M,K] * B[N,K]^T + bias
// A, B bf16 row-major over K. 128x128 tile, BK=64, 256 thr = 4 waves (2x2),
// each wave 64x64 out (4x4 frags of mfma_f32_16x16x32_bf16, fp32 accum).
// LDS tiles [128][64] bf16 with XOR swizzle byte^=((row&7)<<4) (G4 fix).
// EPI=0: fp32 store C + bias        (proj)
// EPI=1: bf16 scatter q/k/v + bias  (qkv; batch-local rows)
// ---------------------------------------------------------------------------
template <int EPI>
__global__ __launch_bounds__(256)
void gemm_bf(const short* __restrict__ A, const short* __restrict__ B,
             const float* __restrict__ bias, float* __restrict__ C,
             int M, int N, int K,
             short* __restrict__ qo, short* __restrict__ ko, short* __restrict__ vo)
{
    __shared__ short As[128][64];
    __shared__ short Bs[128][64];
    const int t  = threadIdx.x;
    const int bm = blockIdx.x, bn = blockIdx.y;
    const int w = t >> 6, lane = t & 63;
    const int lg = lane >> 4, lc = lane & 15;
    const int wr = (w >> 1) * 64, wc = (w & 1) * 64;

    // staging geometry: thread t handles row sr(+32s), 16B at byte-col scb
    const int sr  = t >> 3;
    const int scb = (t & 7) * 16;
    const short* Ap = A + (size_t)(bm * 128 + sr) * K + scb / 2;
    const short* Bp = B + (size_t)(bn * 128 + sr) * K + scb / 2;

    const int swz_r = ((lc & 7) << 4);   // read-side swizzle (row&7 == lc&7)

    f32x4 acc[4][4];
#pragma unroll
    for (int i = 0; i < 4; i++)
#pragma unroll
        for (int j = 0; j < 4; j++) acc[i][j] = (f32x4){0.f, 0.f, 0.f, 0.f};

    bf16x8 ra[4], rb[4];
#pragma unroll
    for (int s = 0; s < 4; s++) {
        ra[s] = *(const bf16x8*)(Ap + (size_t)(s * 32) * K);
        rb[s] = *(const bf16x8*)(Bp + (size_t)(s * 32) * K);
    }

    const int nk = K / 64;
    for (int kt = 0; kt < nk; kt++) {
        __syncthreads();
#pragma unroll
        for (int s = 0; s < 4; s++) {
            const int r = s * 32 + sr;
            const int cb = scb ^ ((r & 7) << 4);
            *(bf16x8*)((char*)&As[r][0] + cb) = ra[s];
            *(bf16x8*)((char*)&Bs[r][0] + cb) = rb[s];
        }
        if (kt + 1 < nk) {
#pragma unroll
            for (int s = 0; s < 4; s++) {
                ra[s] = *(const bf16x8*)(Ap + (size_t)(s * 32) * K + (kt + 1) * 64);
                rb[s] = *(const bf16x8*)(Bp + (size_t)(s * 32) * K + (kt + 1) * 64);
            }
        }
        __syncthreads();
#pragma unroll
        for (int ks = 0; ks < 2; ks++) {
            const int kb = (ks * 64 + lg * 16);
            bf16x8 af[4], bfr[4];
#pragma unroll
            for (int mi = 0; mi < 4; mi++)
                af[mi] = *(const bf16x8*)((char*)&As[wr + mi * 16 + lc][0] + (kb ^ swz_r));
#pragma unroll
            for (int nj = 0; nj < 4; nj++)
                bfr[nj] = *(const bf16x8*)((char*)&Bs[wc + nj * 16 + lc][0] + (kb ^ swz_r));
#pragma unroll
            for (int mi = 0; mi < 4; mi++)
#pragma unroll
                for (int nj = 0; nj < 4; nj++)
                    acc[mi][nj] = __builtin_amdgcn_mfma_f32_16x16x32_bf16(
                        af[mi], bfr[nj], acc[mi][nj], 0, 0, 0);
        }
    }

    // epilogue: D frag: out_row = base + mi*16 + lg*4 + r ; out_col = base + nj*16 + lc
    if (EPI == 0) {
#pragma unroll
        for (int nj = 0; nj < 4; nj++) {
            const int col = bn * 128 + wc + nj * 16 + lc;
            const float bb = bias[col];
#pragma unroll
            for (int mi = 0; mi < 4; mi++)
#pragma unroll
                for (int r = 0; r < 4; r++) {
                    const int row = bm * 128 + wr + mi * 16 + lg * 4 + r;
                    C[(size_t)row * N + col] = acc[mi][nj][r] + bb;
                }
        }
    } else {
#pragma unroll
        for (int nj = 0; nj < 4; nj++) {
            const int col = bn * 128 + wc + nj * 16 + lc;   // 16-col group never straddles h / qkv splits
            const int h  = col / 192;
            const int rr = col - h * 192;
            const float bb = bias[col];
#pragma unroll
            for (int mi = 0; mi < 4; mi++)
#pragma unroll
                for (int r = 0; r < 4; r++) {
                    const int row = bm * 128 + wr + mi * 16 + lg * 4 + r;
                    const int bb_ = row >> 10, nn = row & 1023;
                    const short val = f2bf(acc[mi][nj][r] + bb);
                    const size_t base = ((size_t)(bb_ * NH + h) * NTOK + nn);
                    if (rr < KD)           qo[base * KD + rr] = val;
                    else if (rr < 2 * KD)  ko[base * KD + rr - KD] = val;
                    else                   vo[base * VD + rr - 2 * KD] = val;
                }
        }
    }
}

// ---------------------------------------------------------------------------
// Kernel 3a: transpose v[bh][n][d] (bf16) -> vt[bh][d][n] (bf16), 64x64 tiles
// ---------------------------------------------------------------------------
__global__ __launch_bounds__(256)
void vtrans_kernel(const short* __restrict__ v, short* __restrict__ vt)
{
    __shared__ short T[64][72];
    const int bh  = blockIdx.y;
    const int n0  = (blockIdx.x & 15) * 64;
    const int d0  = (blockIdx.x >> 4) * 64;
    const int t   = threadIdx.x;
    const short* vp  = v  + (size_t)bh * NTOK * VD;
    short*       vtp = vt + (size_t)bh * VD * NTOK;
    {
        const int i = t >> 2, jo = (t & 3) * 16;
        const bf16x8 a = *(const bf16x8*)(vp + (size_t)(n0 + i) * VD + d0 + jo);
        const bf16x8 b = *(const bf16x8*)(vp + (size_t)(n0 + i) * VD + d0 + jo + 8);
        *(bf16x8*)&T[i][jo]     = a;
        *(bf16x8*)&T[i][jo + 8] = b;
    }
    __syncthreads();
    {
        const int j = t >> 2, io = (t & 3) * 16;
        bf16x8 a, b;
#pragma unroll
        for (int c = 0; c < 8; c++) { a[c] = T[io + c][j]; b[c] = T[io + 8 + c][j]; }
        *(bf16x8*)(vtp + (size_t)(d0 + j) * NTOK + n0 + io)     = a;
        *(bf16x8*)(vtp + (size_t)(d0 + j) * NTOK + n0 + io + 8) = b;
    }
}

// ---------------------------------------------------------------------------
// Kernel 3b: MFMA flash attention. 4 waves/block, each owns 16 q-rows.
// abh preloaded to LDS (kills the global->global gather dependency).
// Output ao written as bf16 (feeds proj GEMM A directly).
// ---------------------------------------------------------------------------
__global__ __launch_bounds__(256, 4)
void attn_mfma_kernel(const short* __restrict__ qg, const short* __restrict__ kg,
                      const short* __restrict__ vtg, const float* __restrict__ ab,
                      const int* __restrict__ bidx, short* __restrict__ out)
{
    __shared__ short Ps[4][16][72];   // per-wave P tile [q][m], padded
    __shared__ float ABs[NTOK];       // bias row for this head
    const int id = blockIdx.x;
    const int tt = id >> 3;
    const int qb = tt & 15;
    const int bh = (id & 7) + 8 * (tt >> 4);
    const int b = bh >> 4, h = bh & 15;
    const int t = threadIdx.x;
    const int w = t >> 6, lane = t & 63;
    const int lg = lane >> 4, lc = lane & 15;
    const int n0 = qb * 64 + w * 16;          // wave's q-row base
    const short* qp  = qg  + (size_t)bh * NTOK * KD;
    const short* kp  = kg  + (size_t)bh * NTOK * KD;
    const short* vtp = vtg + (size_t)bh * VD * NTOK;

    ((float4*)ABs)[t] = ((const float4*)(ab + h * NTOK))[t];
    __syncthreads();

    const bf16x8 aq = *(const bf16x8*)(qp + (size_t)(n0 + lc) * KD + lg * 8);

    f32x4 oacc[8];
#pragma unroll
    for (int i = 0; i < 8; i++) oacc[i] = (f32x4){0.f, 0.f, 0.f, 0.f};
    float mrun[4] = {-INFINITY, -INFINITY, -INFINITY, -INFINITY};
    float lrun[4] = {0.f, 0.f, 0.f, 0.f};

    for (int m0 = 0; m0 < NTOK; m0 += 64) {
        // ---- S = Q K^T (4 sub-tiles of 16 keys, K=32 in one mfma each)
        float sv[4][4];                        // [mt][r]
#pragma unroll
        for (int mt = 0; mt < 4; mt++) {
            const bf16x8 bk = *(const bf16x8*)(kp + (size_t)(m0 + mt * 16 + lc) * KD + lg * 8);
            f32x4 d = (f32x4){0.f, 0.f, 0.f, 0.f};
            d = __builtin_amdgcn_mfma_f32_16x16x32_bf16(aq, bk, d, 0, 0, 0);
#pragma unroll
            for (int r = 0; r < 4; r++) sv[mt][r] = d[r];
        }
        // ---- scale + bias (bidx global coalesced, bias gathered from LDS)
#pragma unroll
        for (int mt = 0; mt < 4; mt++)
#pragma unroll
            for (int r = 0; r < 4; r++) {
                const int n = n0 + lg * 4 + r;
                const int m = m0 + mt * 16 + lc;
                sv[mt][r] = sv[mt][r] * SCALE_QK + ABs[bidx[(size_t)n * NTOK + m]];
            }
        // ---- wave-parallel online softmax (rows live in 16-lane groups)
        float alpha[4];
#pragma unroll
        for (int r = 0; r < 4; r++) {
            float m1 = fmaxf(fmaxf(sv[0][r], sv[1][r]), fmaxf(sv[2][r], sv[3][r]));
#pragma unroll
            for (int msk = 1; msk < 16; msk <<= 1) m1 = fmaxf(m1, __shfl_xor(m1, msk));
            const float mn = fmaxf(mrun[r], m1);
            alpha[r] = __expf(mrun[r] - mn);
            mrun[r] = mn;
        }
#pragma unroll
        for (int mt = 0; mt < 4; mt++)
#pragma unroll
            for (int r = 0; r < 4; r++) sv[mt][r] = __expf(sv[mt][r] - mrun[r]);
#pragma unroll
        for (int r = 0; r < 4; r++) {
            float s1 = (sv[0][r] + sv[1][r]) + (sv[2][r] + sv[3][r]);
#pragma unroll
            for (int msk = 1; msk < 16; msk <<= 1) s1 += __shfl_xor(s1, msk);
            lrun[r] = lrun[r] * alpha[r] + s1;
        }
#pragma unroll
        for (int dt = 0; dt < 8; dt++)
#pragma unroll
            for (int r = 0; r < 4; r++) oacc[dt][r] *= alpha[r];
        // ---- P -> bf16 via per-wave LDS (layout change regs->A-frag)
#pragma unroll
        for (int mt = 0; mt < 4; mt++)
#pragma unroll
            for (int r = 0; r < 4; r++)
                Ps[w][lg * 4 + r][mt * 16 + lc] = f2bf(sv[mt][r]);
        // ---- PV accumulate
#pragma unroll
        for (int mt2 = 0; mt2 < 2; mt2++) {
            const bf16x8 ap = *(const bf16x8*)&Ps[w][lc][mt2 * 32 + lg * 8];
#pragma unroll
            for (int dt = 0; dt < 8; dt++) {
                const bf16x8 bv = *(const bf16x8*)(vtp + (size_t)(dt * 16 + lc) * NTOK + m0 + mt2 * 32 + lg * 8);
                oacc[dt] = __builtin_amdgcn_mfma_f32_16x16x32_bf16(ap, bv, oacc[dt], 0, 0, 0);
            }
        }
    }
    // ---- epilogue (bf16 out)
    float inv[4];
#pragma unroll
    for (int r = 0; r < 4; r++) inv[r] = 1.f / lrun[r];
#pragma unroll
    for (int dt = 0; dt < 8; dt++)
#pragma unroll
        for (int r = 0; r < 4; r++)
            out[((size_t)(b * NTOK + n0 + lg * 4 + r) * NH + h) * VD + dt * 16 + lc] =
                f2bf(oacc[dt][r] * inv[r]);
}

// ---------------------------------------------------------------------------
// Launch. ws layout: xn_bf 16MB | wqkv_bf 3MB | wproj_bf 2MB | per-batch:
// q 1 + k 1 + v 4 + vt 4 + ao 4 = 14 MB. g=8 -> 133 MB (known to fit).
// ---------------------------------------------------------------------------
extern "C" void kernel_launch(void* const* d_in, const int* in_sizes, int n_in,
                              void* d_out, int out_size, void* d_ws, size_t ws_size,
                              hipStream_t stream)
{
    const float* x     = (const float*)d_in[0];
    const float* gamma = (const float*)d_in[1];
    const float* beta  = (const float*)d_in[2];
    const float* Wqkv  = (const float*)d_in[3];
    const float* bqkv  = (const float*)d_in[4];
    const float* Wproj = (const float*)d_in[5];
    const float* bproj = (const float*)d_in[6];
    const float* ab    = (const float*)d_in[7];
    const int*   bidx  = (const int*)d_in[8];
    float* out = (float*)d_out;

    const size_t fixed_b = (size_t)NBATCH * NTOK * DIMX * 2   // xn bf16
                         + (size_t)QKVO * DIMX * 2            // Wqkv bf16
                         + (size_t)DIMX * OUTD * 2;           // Wproj bf16
    const size_t per_b = 2ull * NH * NTOK * KD * 2   // q,k bf16
                       + 2ull * NH * NTOK * VD * 2   // v, vt bf16
                       + (size_t)NTOK * OUTD * 2;    // ao bf16
    int g = 0;
    for (int cand = 16; cand >= 1; cand >>= 1)
        if (fixed_b + (size_t)cand * per_b <= ws_size) { g = cand; break; }
    if (g == 0) {
        ws_too_small_kernel<<<(out_size + 255) / 256, 256, 0, stream>>>(out, out_size);
        return;
    }

    char* p = (char*)d_ws;
    short* xnb  = (short*)p;  p += (size_t)NBATCH * NTOK * DIMX * 2;
    short* wqb  = (short*)p;  p += (size_t)QKVO * DIMX * 2;
    short* wpb  = (short*)p;  p += (size_t)DIMX * OUTD * 2;
    short* qb_  = (short*)p;  p += (size_t)g * NH * NTOK * KD * 2;
    short* kb_  = (short*)p;  p += (size_t)g * NH * NTOK * KD * 2;
    short* vb_  = (short*)p;  p += (size_t)g * NH * NTOK * VD * 2;
    short* vtb  = (short*)p;  p += (size_t)g * NH * NTOK * VD * 2;
    short* ao   = (short*)p;

    f2bf_kernel<<<(QKVO * DIMX / 4 + 255) / 256, 256, 0, stream>>>(Wqkv, wqb, QKVO * DIMX / 4);
    f2bf_kernel<<<(DIMX * OUTD / 4 + 255) / 256, 256, 0, stream>>>(Wproj, wpb, DIMX * OUTD / 4);
    ln_kernel<<<16384, 128, 0, stream>>>(x, gamma, beta, xnb);

    for (int b0 = 0; b0 < NBATCH; b0 += g) {
        short* xrows = xnb + (size_t)b0 * NTOK * DIMX;
        gemm_bf<1><<<dim3(g * 8, 24), 256, 0, stream>>>(
            xrows, wqb, bqkv, nullptr, g * NTOK, QKVO, DIMX, qb_, kb_, vb_);
        vtrans_kernel<<<dim3(32, g * 16), 256, 0, stream>>>(vb_, vtb);
        attn_mfma_kernel<<<16 * g * 16, 256, 0, stream>>>(qb_, kb_, vtb, ab, bidx, ao);
        gemm_bf<0><<<dim3(g * 8, 4), 256, 0, stream>>>(
            ao, wpb, bproj, out + (size_t)b0 * NTOK * DIMX,
            g * NTOK, DIMX, OUTD, nullptr, nullptr, nullptr);
    }
}

// Round 10
// 784.161 us; speedup vs baseline: 4.0510x; 1.2737x over previous
//
#include <hip/hip_runtime.h>
#include <math.h>
#include <stdint.h>

// Problem constants
#define DIMX 512
#define KD 32
#define NH 16
#define VD 128
#define NTOK 1024
#define NBATCH 16
#define QKVO 3072   // NH*(VD+2*KD)
#define OUTD 2048   // NH*VD
#define SCALE_QK 0.17677669529663687f
#define LN_EPS 1e-5f

typedef __attribute__((ext_vector_type(8))) short bf16x8;   // 8 bf16 in 4 VGPRs
typedef __attribute__((ext_vector_type(4))) short short4v;  // 4 bf16 (8B)
typedef __attribute__((ext_vector_type(4))) float f32x4;

__device__ __forceinline__ short f2bf(float f) {   // fp32 -> bf16 RNE
    uint32_t u = __builtin_bit_cast(uint32_t, f);
    u += 0x7FFFu + ((u >> 16) & 1u);
    return (short)(u >> 16);
}

// ---------------------------------------------------------------------------
// Guard kernel: marks output when workspace is too small (diagnostic, no fault)
// ---------------------------------------------------------------------------
__global__ void ws_too_small_kernel(float* out, int n)
{
    int i = blockIdx.x * blockDim.x + threadIdx.x;
    if (i < n) out[i] = -12345.0f;
}

// ---------------------------------------------------------------------------
// Kernel 0: fp32 -> bf16 weight conversion (vectorized, n multiple of 4)
// ---------------------------------------------------------------------------
__global__ __launch_bounds__(256)
void f2bf_kernel(const float* __restrict__ in, short* __restrict__ out, int n4)
{
    int i = blockIdx.x * blockDim.x + threadIdx.x;
    if (i < n4) {
        const float4 v = ((const float4*)in)[i];
        short4v s;
        s[0] = f2bf(v.x); s[1] = f2bf(v.y); s[2] = f2bf(v.z); s[3] = f2bf(v.w);
        ((short4v*)out)[i] = s;
    }
}

// ---------------------------------------------------------------------------
// Kernel 1: LayerNorm, one block (128 thr) per row of 512 floats -> bf16 out
// ---------------------------------------------------------------------------
__global__ __launch_bounds__(128)
void ln_kernel(const float* __restrict__ x, const float* __restrict__ g,
               const float* __restrict__ be, short* __restrict__ xn)
{
    const size_t row = blockIdx.x;
    const int t = threadIdx.x;
    const float4 v = ((const float4*)(x + row * DIMX))[t];
    float s  = v.x + v.y + v.z + v.w;
    float ss = v.x*v.x + v.y*v.y + v.z*v.z + v.w*v.w;
#pragma unroll
    for (int o = 32; o; o >>= 1) { s += __shfl_down(s, o); ss += __shfl_down(ss, o); }
    __shared__ float sb[4];
    if ((t & 63) == 0) { sb[t >> 6] = s; sb[2 + (t >> 6)] = ss; }
    __syncthreads();
    s = sb[0] + sb[1]; ss = sb[2] + sb[3];
    const float mu = s * (1.f / DIMX);
    const float rs = rsqrtf(ss * (1.f / DIMX) - mu * mu + LN_EPS);
    const float4 gv = ((const float4*)g)[t];
    const float4 bv = ((const float4*)be)[t];
    short4v o;
    o[0] = f2bf((v.x - mu) * rs * gv.x + bv.x);
    o[1] = f2bf((v.y - mu) * rs * gv.y + bv.y);
    o[2] = f2bf((v.z - mu) * rs * gv.z + bv.z);
    o[3] = f2bf((v.w - mu) * rs * gv.w + bv.w);
    *(short4v*)(xn + row * DIMX + t * 4) = o;
}

// ---------------------------------------------------------------------------
// Kernel 2/4: bf16 MFMA GEMM.  C[M,N] = A[M,K] * B[N,K]^T + bias
// (unchanged from round 7)
// ---------------------------------------------------------------------------
template <int EPI>
__global__ __launch_bounds__(256)
void gemm_bf(const short* __restrict__ A, const short* __restrict__ B,
             const float* __restrict__ bias, float* __restrict__ C,
             int M, int N, int K,
             short* __restrict__ qo, short* __restrict__ ko, short* __restrict__ vo)
{
    __shared__ short As[128][64];
    __shared__ short Bs[128][64];
    const int t  = threadIdx.x;
    const int bm = blockIdx.x, bn = blockIdx.y;
    const int w = t >> 6, lane = t & 63;
    const int lg = lane >> 4, lc = lane & 15;
    const int wr = (w >> 1) * 64, wc = (w & 1) * 64;

    const int sr  = t >> 3;
    const int scb = (t & 7) * 16;
    const short* Ap = A + (size_t)(bm * 128 + sr) * K + scb / 2;
    const short* Bp = B + (size_t)(bn * 128 + sr) * K + scb / 2;

    const int swz_r = ((lc & 7) << 4);

    f32x4 acc[4][4];
#pragma unroll
    for (int i = 0; i < 4; i++)
#pragma unroll
        for (int j = 0; j < 4; j++) acc[i][j] = (f32x4){0.f, 0.f, 0.f, 0.f};

    bf16x8 ra[4], rb[4];
#pragma unroll
    for (int s = 0; s < 4; s++) {
        ra[s] = *(const bf16x8*)(Ap + (size_t)(s * 32) * K);
        rb[s] = *(const bf16x8*)(Bp + (size_t)(s * 32) * K);
    }

    const int nk = K / 64;
    for (int kt = 0; kt < nk; kt++) {
        __syncthreads();
#pragma unroll
        for (int s = 0; s < 4; s++) {
            const int r = s * 32 + sr;
            const int cb = scb ^ ((r & 7) << 4);
            *(bf16x8*)((char*)&As[r][0] + cb) = ra[s];
            *(bf16x8*)((char*)&Bs[r][0] + cb) = rb[s];
        }
        if (kt + 1 < nk) {
#pragma unroll
            for (int s = 0; s < 4; s++) {
                ra[s] = *(const bf16x8*)(Ap + (size_t)(s * 32) * K + (kt + 1) * 64);
                rb[s] = *(const bf16x8*)(Bp + (size_t)(s * 32) * K + (kt + 1) * 64);
            }
        }
        __syncthreads();
#pragma unroll
        for (int ks = 0; ks < 2; ks++) {
            const int kb = (ks * 64 + lg * 16);
            bf16x8 af[4], bfr[4];
#pragma unroll
            for (int mi = 0; mi < 4; mi++)
                af[mi] = *(const bf16x8*)((char*)&As[wr + mi * 16 + lc][0] + (kb ^ swz_r));
#pragma unroll
            for (int nj = 0; nj < 4; nj++)
                bfr[nj] = *(const bf16x8*)((char*)&Bs[wc + nj * 16 + lc][0] + (kb ^ swz_r));
#pragma unroll
            for (int mi = 0; mi < 4; mi++)
#pragma unroll
                for (int nj = 0; nj < 4; nj++)
                    acc[mi][nj] = __builtin_amdgcn_mfma_f32_16x16x32_bf16(
                        af[mi], bfr[nj], acc[mi][nj], 0, 0, 0);
        }
    }

    if (EPI == 0) {
#pragma unroll
        for (int nj = 0; nj < 4; nj++) {
            const int col = bn * 128 + wc + nj * 16 + lc;
            const float bb = bias[col];
#pragma unroll
            for (int mi = 0; mi < 4; mi++)
#pragma unroll
                for (int r = 0; r < 4; r++) {
                    const int row = bm * 128 + wr + mi * 16 + lg * 4 + r;
                    C[(size_t)row * N + col] = acc[mi][nj][r] + bb;
                }
        }
    } else {
#pragma unroll
        for (int nj = 0; nj < 4; nj++) {
            const int col = bn * 128 + wc + nj * 16 + lc;
            const int h  = col / 192;
            const int rr = col - h * 192;
            const float bb = bias[col];
#pragma unroll
            for (int mi = 0; mi < 4; mi++)
#pragma unroll
                for (int r = 0; r < 4; r++) {
                    const int row = bm * 128 + wr + mi * 16 + lg * 4 + r;
                    const int bb_ = row >> 10, nn = row & 1023;
                    const short val = f2bf(acc[mi][nj][r] + bb);
                    const size_t base = ((size_t)(bb_ * NH + h) * NTOK + nn);
                    if (rr < KD)           qo[base * KD + rr] = val;
                    else if (rr < 2 * KD)  ko[base * KD + rr - KD] = val;
                    else                   vo[base * VD + rr - 2 * KD] = val;
                }
        }
    }
}

// ---------------------------------------------------------------------------
// Kernel 3a: transpose v[bh][n][d] (bf16) -> vt[bh][d][n] (bf16), 64x64 tiles
// ---------------------------------------------------------------------------
__global__ __launch_bounds__(256)
void vtrans_kernel(const short* __restrict__ v, short* __restrict__ vt)
{
    __shared__ short T[64][72];
    const int bh  = blockIdx.y;
    const int n0  = (blockIdx.x & 15) * 64;
    const int d0  = (blockIdx.x >> 4) * 64;
    const int t   = threadIdx.x;
    const short* vp  = v  + (size_t)bh * NTOK * VD;
    short*       vtp = vt + (size_t)bh * VD * NTOK;
    {
        const int i = t >> 2, jo = (t & 3) * 16;
        const bf16x8 a = *(const bf16x8*)(vp + (size_t)(n0 + i) * VD + d0 + jo);
        const bf16x8 b = *(const bf16x8*)(vp + (size_t)(n0 + i) * VD + d0 + jo + 8);
        *(bf16x8*)&T[i][jo]     = a;
        *(bf16x8*)&T[i][jo + 8] = b;
    }
    __syncthreads();
    {
        const int j = t >> 2, io = (t & 3) * 16;
        bf16x8 a, b;
#pragma unroll
        for (int c = 0; c < 8; c++) { a[c] = T[io + c][j]; b[c] = T[io + 8 + c][j]; }
        *(bf16x8*)(vtp + (size_t)(d0 + j) * NTOK + n0 + io)     = a;
        *(bf16x8*)(vtp + (size_t)(d0 + j) * NTOK + n0 + io + 8) = b;
    }
}

// ---------------------------------------------------------------------------
// Kernel 3b: MFMA flash attention, pipelined.
//  - bias index computed arithmetically: idx = |n/32 - m/32|*32 + |n%32 - m%32|
//    (meshgrid structure of bias_idxs) and gathered from 4KB LDS -> NO global
//    bidx dependency in the loop.
//  - K-fragments and bias values prefetched one 64-key tile ahead (registers).
//  - defer-max (THR=8): skip O/l rescale while tile max doesn't grow.
//  - Ps pad 68 (write banks all-distinct, 2-way free).
// ---------------------------------------------------------------------------
__global__ __launch_bounds__(256, 4)
void attn_mfma_kernel(const short* __restrict__ qg, const short* __restrict__ kg,
                      const short* __restrict__ vtg, const float* __restrict__ ab,
                      short* __restrict__ out)
{
    __shared__ short Ps[4][16][68];   // per-wave P tile [q][m]
    __shared__ float ABs[NTOK];       // bias table row for this head
    const int id = blockIdx.x;
    const int tt = id >> 3;
    const int qb = tt & 15;
    const int bh = (id & 7) + 8 * (tt >> 4);
    const int b = bh >> 4, h = bh & 15;
    const int t = threadIdx.x;
    const int w = t >> 6, lane = t & 63;
    const int lg = lane >> 4, lc = lane & 15;
    const int n0 = qb * 64 + w * 16;          // wave's q-row base
    const short* qp  = qg  + (size_t)bh * NTOK * KD;
    const short* kp  = kg  + (size_t)bh * NTOK * KD;
    const short* vtp = vtg + (size_t)bh * VD * NTOK;

    ((float4*)ABs)[t] = ((const float4*)(ab + h * NTOK))[t];
    __syncthreads();

    const bf16x8 aq = *(const bf16x8*)(qp + (size_t)(n0 + lc) * KD + lg * 8);

    // q-row spatial coords (n = n0 + lg*4 + r)
    int xi[4], yi[4];
#pragma unroll
    for (int r = 0; r < 4; r++) { const int n = n0 + lg * 4 + r; xi[r] = n >> 5; yi[r] = n & 31; }

    f32x4 oacc[8];
#pragma unroll
    for (int i = 0; i < 8; i++) oacc[i] = (f32x4){0.f, 0.f, 0.f, 0.f};
    float mrun[4] = {-3e38f, -3e38f, -3e38f, -3e38f};
    float lrun[4] = {0.f, 0.f, 0.f, 0.f};

    // prefetch tile 0: K fragments + bias gathers
    bf16x8 kf[4];
    float bcur[4][4];
#pragma unroll
    for (int mt = 0; mt < 4; mt++) {
        kf[mt] = *(const bf16x8*)(kp + (size_t)(mt * 16 + lc) * KD + lg * 8);
        const int m = mt * 16 + lc, xj = m >> 5, yj = m & 31;
#pragma unroll
        for (int r = 0; r < 4; r++)
            bcur[mt][r] = ABs[abs(xi[r] - xj) * 32 + abs(yi[r] - yj)];
    }

    for (int m0 = 0; m0 < NTOK; m0 += 64) {
        // ---- S = Q K^T from prefetched fragments
        float sv[4][4];
#pragma unroll
        for (int mt = 0; mt < 4; mt++) {
            f32x4 d = (f32x4){0.f, 0.f, 0.f, 0.f};
            d = __builtin_amdgcn_mfma_f32_16x16x32_bf16(aq, kf[mt], d, 0, 0, 0);
#pragma unroll
            for (int r = 0; r < 4; r++) sv[mt][r] = d[r] * SCALE_QK + bcur[mt][r];
        }
        // ---- prefetch tile t+1 (completes under softmax+PV)
        const int m1 = m0 + 64;
        if (m1 < NTOK) {
#pragma unroll
            for (int mt = 0; mt < 4; mt++) {
                kf[mt] = *(const bf16x8*)(kp + (size_t)(m1 + mt * 16 + lc) * KD + lg * 8);
                const int m = m1 + mt * 16 + lc, xj = m >> 5, yj = m & 31;
#pragma unroll
                for (int r = 0; r < 4; r++)
                    bcur[mt][r] = ABs[abs(xi[r] - xj) * 32 + abs(yi[r] - yj)];
            }
        }
        // ---- online softmax with defer-max (rows live across 16-lane groups)
        float pmax[4];
#pragma unroll
        for (int r = 0; r < 4; r++) {
            float m1v = fmaxf(fmaxf(sv[0][r], sv[1][r]), fmaxf(sv[2][r], sv[3][r]));
#pragma unroll
            for (int msk = 1; msk < 16; msk <<= 1) m1v = fmaxf(m1v, __shfl_xor(m1v, msk));
            pmax[r] = m1v;
        }
        const bool ok = (pmax[0] <= mrun[0] + 8.f) && (pmax[1] <= mrun[1] + 8.f) &&
                        (pmax[2] <= mrun[2] + 8.f) && (pmax[3] <= mrun[3] + 8.f);
        if (!__all(ok)) {
#pragma unroll
            for (int r = 0; r < 4; r++) {
                const float mn = fmaxf(mrun[r], pmax[r]);
                const float alpha = __expf(mrun[r] - mn);
                mrun[r] = mn;
                lrun[r] *= alpha;
#pragma unroll
                for (int dt = 0; dt < 8; dt++) oacc[dt][r] *= alpha;
            }
        }
#pragma unroll
        for (int mt = 0; mt < 4; mt++)
#pragma unroll
            for (int r = 0; r < 4; r++) sv[mt][r] = __expf(sv[mt][r] - mrun[r]);
#pragma unroll
        for (int r = 0; r < 4; r++) {
            float s1 = (sv[0][r] + sv[1][r]) + (sv[2][r] + sv[3][r]);
#pragma unroll
            for (int msk = 1; msk < 16; msk <<= 1) s1 += __shfl_xor(s1, msk);
            lrun[r] += s1;
        }
        // ---- P -> bf16 via per-wave LDS (layout change regs -> A-frag)
#pragma unroll
        for (int mt = 0; mt < 4; mt++)
#pragma unroll
            for (int r = 0; r < 4; r++)
                Ps[w][lg * 4 + r][mt * 16 + lc] = f2bf(sv[mt][r]);
        // ---- PV accumulate
#pragma unroll
        for (int mt2 = 0; mt2 < 2; mt2++) {
            const bf16x8 ap = *(const bf16x8*)&Ps[w][lc][mt2 * 32 + lg * 8];
#pragma unroll
            for (int dt = 0; dt < 8; dt++) {
                const bf16x8 bv = *(const bf16x8*)(vtp + (size_t)(dt * 16 + lc) * NTOK + m0 + mt2 * 32 + lg * 8);
                oacc[dt] = __builtin_amdgcn_mfma_f32_16x16x32_bf16(ap, bv, oacc[dt], 0, 0, 0);
            }
        }
    }
    // ---- epilogue (bf16 out)
    float inv[4];
#pragma unroll
    for (int r = 0; r < 4; r++) inv[r] = 1.f / lrun[r];
#pragma unroll
    for (int dt = 0; dt < 8; dt++)
#pragma unroll
        for (int r = 0; r < 4; r++)
            out[((size_t)(b * NTOK + n0 + lg * 4 + r) * NH + h) * VD + dt * 16 + lc] =
                f2bf(oacc[dt][r] * inv[r]);
}

// ---------------------------------------------------------------------------
// Launch. ws layout identical to round 7.
// ---------------------------------------------------------------------------
extern "C" void kernel_launch(void* const* d_in, const int* in_sizes, int n_in,
                              void* d_out, int out_size, void* d_ws, size_t ws_size,
                              hipStream_t stream)
{
    const float* x     = (const float*)d_in[0];
    const float* gamma = (const float*)d_in[1];
    const float* beta  = (const float*)d_in[2];
    const float* Wqkv  = (const float*)d_in[3];
    const float* bqkv  = (const float*)d_in[4];
    const float* Wproj = (const float*)d_in[5];
    const float* bproj = (const float*)d_in[6];
    const float* ab    = (const float*)d_in[7];
    float* out = (float*)d_out;

    const size_t fixed_b = (size_t)NBATCH * NTOK * DIMX * 2   // xn bf16
                         + (size_t)QKVO * DIMX * 2            // Wqkv bf16
                         + (size_t)DIMX * OUTD * 2;           // Wproj bf16
    const size_t per_b = 2ull * NH * NTOK * KD * 2   // q,k bf16
                       + 2ull * NH * NTOK * VD * 2   // v, vt bf16
                       + (size_t)NTOK * OUTD * 2;    // ao bf16
    int g = 0;
    for (int cand = 16; cand >= 1; cand >>= 1)
        if (fixed_b + (size_t)cand * per_b <= ws_size) { g = cand; break; }
    if (g == 0) {
        ws_too_small_kernel<<<(out_size + 255) / 256, 256, 0, stream>>>(out, out_size);
        return;
    }

    char* p = (char*)d_ws;
    short* xnb  = (short*)p;  p += (size_t)NBATCH * NTOK * DIMX * 2;
    short* wqb  = (short*)p;  p += (size_t)QKVO * DIMX * 2;
    short* wpb  = (short*)p;  p += (size_t)DIMX * OUTD * 2;
    short* qb_  = (short*)p;  p += (size_t)g * NH * NTOK * KD * 2;
    short* kb_  = (short*)p;  p += (size_t)g * NH * NTOK * KD * 2;
    short* vb_  = (short*)p;  p += (size_t)g * NH * NTOK * VD * 2;
    short* vtb  = (short*)p;  p += (size_t)g * NH * NTOK * VD * 2;
    short* ao   = (short*)p;

    f2bf_kernel<<<(QKVO * DIMX / 4 + 255) / 256, 256, 0, stream>>>(Wqkv, wqb, QKVO * DIMX / 4);
    f2bf_kernel<<<(DIMX * OUTD / 4 + 255) / 256, 256, 0, stream>>>(Wproj, wpb, DIMX * OUTD / 4);
    ln_kernel<<<16384, 128, 0, stream>>>(x, gamma, beta, xnb);

    for (int b0 = 0; b0 < NBATCH; b0 += g) {
        short* xrows = xnb + (size_t)b0 * NTOK * DIMX;
        gemm_bf<1><<<dim3(g * 8, 24), 256, 0, stream>>>(
            xrows, wqb, bqkv, nullptr, g * NTOK, QKVO, DIMX, qb_, kb_, vb_);
        vtrans_kernel<<<dim3(32, g * 16), 256, 0, stream>>>(vb_, vtb);
        attn_mfma_kernel<<<16 * g * 16, 256, 0, stream>>>(qb_, kb_, vtb, ab, ao);
        gemm_bf<0><<<dim3(g * 8, 4), 256, 0, stream>>>(
            ao, wpb, bproj, out + (size_t)b0 * NTOK * DIMX,
            g * NTOK, DIMX, OUTD, nullptr, nullptr, nullptr);
    }
}